// Round 4
// baseline (41180.368 us; speedup 1.0000x reference)
//
#include <hip/hip_runtime.h>
#include <hip/hip_bf16.h>

#define NB 64
#define NS 512
#define NI 64
#define NE 256
#define ND 256
#define N4E 1024
#define N4D 1024
#define NTE 512   // 2*E
#define G 4
#define SLICE 128 // NS/G
#define CELLS 64  // ND/G

__device__ __forceinline__ float fsig(float x){
    return __fdividef(1.f, 1.f + __expf(-x));
}
__device__ __forceinline__ float ftanh(float x){
    x = fminf(10.f, fmaxf(-10.f, x));
    float e = __expf(2.f*x);
    return 1.f - __fdividef(2.f, e + 1.f);
}
__device__ __forceinline__ float wave_sum(float v){
    #pragma unroll
    for (int o=32;o>0;o>>=1) v += __shfl_xor(v, o, 64);
    return v;
}
__device__ __forceinline__ float wave_max(float v){
    #pragma unroll
    for (int o=32;o>0;o>>=1) v = fmaxf(v, __shfl_xor(v, o, 64));
    return v;
}
__device__ __forceinline__ float blo(unsigned u){ return __uint_as_float(u<<16); }
__device__ __forceinline__ float bhi(unsigned u){ return __uint_as_float(u & 0xffff0000u); }
__device__ __forceinline__ unsigned short bfbits(float f){
    __hip_bfloat16 h = __float2bfloat16(f);
    return *(unsigned short*)&h;
}
// relaxed agent-scope accessors: single instructions, no cache-wide ops
__device__ __forceinline__ float ld_agf(const float* p){
    return __hip_atomic_load(p, __ATOMIC_RELAXED, __HIP_MEMORY_SCOPE_AGENT);
}
__device__ __forceinline__ void st_agf(float* p, float v){
    __hip_atomic_store(p, v, __ATOMIC_RELAXED, __HIP_MEMORY_SCOPE_AGENT);
}

__device__ __forceinline__ void groupbar(unsigned* c, unsigned tgt, int tid){
    __syncthreads();
    if (tid == 0){
        __hip_atomic_fetch_add(c, 1u, __ATOMIC_RELAXED, __HIP_MEMORY_SCOPE_AGENT);
        while (__hip_atomic_load(c, __ATOMIC_RELAXED, __HIP_MEMORY_SCOPE_AGENT) < tgt)
            __builtin_amdgcn_s_sleep(2);
    }
    __syncthreads();
}

// fp32 transpose: dst[c*R + r] = src[r*ld + off + c]
__global__ void k_transpose(float* __restrict__ dst, const float* __restrict__ src,
                            int R, int C, int ld, int off){
    int idx = blockIdx.x*256 + threadIdx.x;
    if (idx >= R*C) return;
    int r = idx / C, c = idx - r*C;
    dst[(size_t)c*R + r] = src[(size_t)r*ld + off + c];
}
// bf16 transpose
__global__ void k_transpose16(__hip_bfloat16* __restrict__ dst, const float* __restrict__ src,
                              int R, int C, int ld, int off){
    int idx = blockIdx.x*256 + threadIdx.x;
    if (idx >= R*C) return;
    int r = idx / C, c = idx - r*C;
    dst[(size_t)c*R + r] = __float2bfloat16(src[(size_t)r*ld + off + c]);
}

// pack adjacent fp32 pairs into bf16x2 u32: dst[r*Cp+k] = (src[r][2k], src[r][2k+1])
__global__ void k_pack_pairs(unsigned* __restrict__ dst, const float* __restrict__ src,
                             int n, int Cp){
    int idx = blockIdx.x*256 + threadIdx.x;
    if (idx >= n) return;
    int r = idx / Cp, k = idx - r*Cp;
    const float* s = src + (size_t)r*2*Cp + 2*k;
    dst[idx] = (unsigned)bfbits(s[0]) | ((unsigned)bfbits(s[1])<<16);
}

__global__ void k_pack_wy(float* __restrict__ wy, const float* __restrict__ Wih_d){
    int j = blockIdx.x*256 + threadIdx.x;
    if (j < N4D) wy[j] = Wih_d[(size_t)j*(NTE+1)];
}

// WdTg16[q][e][jj] = bf16(Wih_d[ (jj>>6)*256 + q*64 + (jj&63) ][ 1 + e ])
__global__ void k_pack_wdtg(__hip_bfloat16* __restrict__ dst, const float* __restrict__ Wih_d){
    int idx = blockIdx.x*256 + threadIdx.x;   // total 4*512*256 = 524288
    int q = idx >> 17, rem = idx & 131071;
    int e = rem >> 8, jj = rem & 255;
    int j = ((jj>>6)<<8) + (q<<6) + (jj&63);
    dst[idx] = __float2bfloat16(Wih_d[(size_t)j*(NTE+1) + 1 + e]);
}

// zc[b][j] = b_d[j] + sum_d h0d[b][d] * Whh_d[j][d]   (WhhTd is [d][j] fp32)
__global__ void k_zc(float* __restrict__ zc, const float* __restrict__ WhhTd,
                     const float* __restrict__ h0d, const float* __restrict__ b_d){
    int b = blockIdx.x, tid = threadIdx.x;
    __shared__ float h0[ND];
    if (tid < ND) h0[tid] = h0d[b*ND + tid];
    __syncthreads();
    for (int j = tid; j < N4D; j += 256){
        float acc = b_d[j];
        #pragma unroll 8
        for (int d=0; d<ND; ++d) acc = fmaf(h0[d], WhhTd[d*N4D + j], acc);
        zc[b*N4D + j] = acc;
    }
}

__global__ void k_dec_init(float* __restrict__ hG, float* __restrict__ yG,
                           unsigned* __restrict__ ctr, const float* __restrict__ dec_h0){
    int b = blockIdx.x, tid = threadIdx.x;
    hG[b*ND + tid] = dec_h0[b*ND + tid];
    if (tid < G) yG[b*G + tid] = 0.f;
    if (tid == 0) ctr[b] = 0u;
}

// Encoder v2: 128 blocks = (dir,b), 1024 threads (one gate-row j per thread).
// Wih row + bias in registers; Whh row streamed as uint4 from L2; h/x fp32 in LDS.
__global__ __launch_bounds__(1024, 4) void k_enc(
    const float* __restrict__ x, const float* __restrict__ eh0, const float* __restrict__ ec0,
    const unsigned* __restrict__ whhPKf, const unsigned* __restrict__ wihPKf, const float* __restrict__ bf,
    const unsigned* __restrict__ whhPKb, const unsigned* __restrict__ wihPKb, const float* __restrict__ bb,
    unsigned* __restrict__ eo32)
{
    int bid = blockIdx.x;
    int b = bid & 63, dir = bid >> 6;
    int tid = threadIdx.x;
    const unsigned* whhPK = dir ? whhPKb : whhPKf;
    const unsigned* wihPK = dir ? wihPKb : wihPKf;
    const float* bias = dir ? bb : bf;

    __shared__ __align__(16) float h_l[NE];
    __shared__ __align__(16) float xt[2][NI];
    __shared__ float z_l[N4E];

    unsigned wih_r[32];
    {
        const uint4* wr = (const uint4*)(wihPK + (size_t)tid*32);
        #pragma unroll
        for (int k=0;k<8;++k) ((uint4*)wih_r)[k] = wr[k];
    }
    const uint4* wrow = (const uint4*)(whhPK + (size_t)tid*128);
    float bias_r = bias[tid];

    float c0r=0.f, c1r=0.f;
    if (tid < 128){
        h_l[2*tid]   = eh0[(dir*NB+b)*NE + 2*tid];
        h_l[2*tid+1] = eh0[(dir*NB+b)*NE + 2*tid+1];
        c0r = ec0[(dir*NB+b)*NE + 2*tid];
        c1r = ec0[(dir*NB+b)*NE + 2*tid+1];
    }
    {
        int st0 = dir ? (NS-1) : 0;
        if (tid < 16) ((float4*)xt[0])[tid] = ((const float4*)(x + ((size_t)b*NS+st0)*NI))[tid];
    }
    __syncthreads();

    for (int t=0;t<NS;++t){
        int st = dir ? (NS-1-t) : t;
        float4 xpre = make_float4(0.f,0.f,0.f,0.f);
        if (t+1 < NS && tid < 16){
            int stn = dir ? (NS-2-t) : (t+1);
            xpre = ((const float4*)(x + ((size_t)b*NS+stn)*NI))[tid];
        }
        const float* xc = xt[t&1];
        float a0=bias_r, a1=0.f, a2=0.f, a3=0.f;
        #pragma unroll
        for (int k=0;k<16;++k){
            float4 xv = ((const float4*)xc)[k];
            unsigned w0 = wih_r[2*k], w1 = wih_r[2*k+1];
            a0 = fmaf(xv.x, blo(w0), a0);
            a1 = fmaf(xv.y, bhi(w0), a1);
            a2 = fmaf(xv.z, blo(w1), a2);
            a3 = fmaf(xv.w, bhi(w1), a3);
        }
        const float4* h4 = (const float4*)h_l;
        #pragma unroll
        for (int kk=0;kk<32;++kk){
            uint4 w = wrow[kk];
            float4 ha = h4[2*kk], hb = h4[2*kk+1];
            a0 = fmaf(ha.x, blo(w.x), a0);
            a1 = fmaf(ha.y, bhi(w.x), a1);
            a2 = fmaf(ha.z, blo(w.y), a2);
            a3 = fmaf(ha.w, bhi(w.y), a3);
            a0 = fmaf(hb.x, blo(w.z), a0);
            a1 = fmaf(hb.y, bhi(w.z), a1);
            a2 = fmaf(hb.z, blo(w.w), a2);
            a3 = fmaf(hb.w, bhi(w.w), a3);
        }
        z_l[tid] = (a0+a1)+(a2+a3);
        if (t+1 < NS && tid < 16) ((float4*)xt[(t+1)&1])[tid] = xpre;
        __syncthreads();
        if (tid < 128){
            int d0 = 2*tid, d1 = 2*tid+1;
            float zi0=z_l[d0], zf0=z_l[NE+d0], zg0=z_l[2*NE+d0], zo0=z_l[3*NE+d0];
            float zi1=z_l[d1], zf1=z_l[NE+d1], zg1=z_l[2*NE+d1], zo1=z_l[3*NE+d1];
            c0r = fsig(zf0)*c0r + fsig(zi0)*ftanh(zg0);
            c1r = fsig(zf1)*c1r + fsig(zi1)*ftanh(zg1);
            float h0 = fsig(zo0)*ftanh(c0r);
            float h1 = fsig(zo1)*ftanh(c1r);
            h_l[d0]=h0; h_l[d1]=h1;
            eo32[((size_t)b*NS+st)*(NTE/2) + dir*(NE/2) + tid] =
                (unsigned)bfbits(h0) | ((unsigned)bfbits(h1)<<16);
        }
        __syncthreads();
    }
}

// ep_pk[b][q][dp][s] (u32 = bf16 pair d=2dp,2dp+1) from bf16 enc_out.
__global__ __launch_bounds__(256) void k_encproj(const unsigned* __restrict__ eo32,
        const float* __restrict__ WeT, const float* __restrict__ b_attn,
        unsigned short* __restrict__ ep_pk16){
    int b = blockIdx.y, s0 = blockIdx.x*16, tid = threadIdx.x;
    __shared__ float tile[16*NTE];
    {
        const unsigned* eop = eo32 + (size_t)(b*NS + s0)*256;
        for (int k=0;k<32;++k){
            int wi = k*256 + tid;
            unsigned w = eop[wi];
            int sl = wi>>8, ew = wi&255;
            tile[sl*NTE + 2*ew]   = blo(w);
            tile[sl*NTE + 2*ew+1] = bhi(w);
        }
    }
    __syncthreads();
    float acc[16];
    float ba = b_attn[tid];
    #pragma unroll
    for (int sl=0;sl<16;++sl) acc[sl]=ba;
    #pragma unroll 4
    for (int e4=0;e4<128;++e4){
        float w0 = WeT[(4*e4+0)*ND+tid];
        float w1 = WeT[(4*e4+1)*ND+tid];
        float w2 = WeT[(4*e4+2)*ND+tid];
        float w3 = WeT[(4*e4+3)*ND+tid];
        #pragma unroll
        for (int sl=0;sl<16;++sl){
            const float4 tv = *(const float4*)&tile[sl*NTE + 4*e4];
            acc[sl] = fmaf(tv.x,w0,fmaf(tv.y,w1,fmaf(tv.z,w2,fmaf(tv.w,w3,acc[sl]))));
        }
    }
    #pragma unroll
    for (int sl=0;sl<16;++sl){
        int s = s0+sl;
        size_t wdi = ((size_t)(b*4 + (s>>7))*128 + (tid>>1))*128 + (s&127);
        ep_pk16[wdi*2 + (tid&1)] = bfbits(acc[sl]);
    }
}

// Cooperative decoder: 256 blocks = 64 batches x 4 slices, 1024 threads.
__global__ __launch_bounds__(1024, 4) void k_dec(
    const unsigned* __restrict__ eo32,     // [b*s][256] bf16 e-pairs
    const unsigned* __restrict__ ep_pk,    // [b][q][128 dp][128 s] u32
    const unsigned* __restrict__ WhTp,     // [k 256][128] bf16 d-pairs
    const float* __restrict__ v,
    const float* __restrict__ zc, const float* __restrict__ wy,
    const unsigned* __restrict__ WdTp_all, // [q][512 e][128] bf16 jj-pairs
    const float* __restrict__ dec_c0,
    const float* __restrict__ W_lin, const float* __restrict__ b_lin,
    float* __restrict__ hG, float* __restrict__ yG,
    float* __restrict__ ctxG, float* __restrict__ msG,
    unsigned* __restrict__ ctr,
    float* __restrict__ out)
{
    int bid = blockIdx.x;
    int b = bid & 63, q = bid >> 6;
    int tid = threadIdx.x;

    __shared__ unsigned ep_lds[16384];   // 64 KB: [128 dp][128 s]
    __shared__ float part[2048];
    __shared__ float h_l[ND];
    __shared__ float2 hv[ND];            // (v[d], hproj[d])
    __shared__ float v_l[ND];
    __shared__ float scores_l[SLICE];
    __shared__ float ctx_l[NTE];
    __shared__ float z_l[256], zc_l[256], wy_l[256];
    __shared__ float c0_l[CELLS], wlh_l[CELLS], wlc_l[SLICE];
    __shared__ float msbuf[8];
    __shared__ float wred[16];
    __shared__ float smax, yprev;

    const unsigned* WdTp = WdTp_all + (size_t)q*NTE*128;

    for (int i=tid; i<16384; i+=1024)
        ep_lds[i] = ep_pk[(size_t)(b*4+q)*16384 + i];
    unsigned eo_reg[32];
    {
        int ep2 = tid & 255, sq = tid >> 8;
        const unsigned* eop = eo32 + (size_t)(b*NS + q*SLICE + sq*32)*256 + ep2;
        #pragma unroll
        for (int ss=0; ss<32; ++ss) eo_reg[ss] = eop[(size_t)ss*256];
    }
    if (tid < 256){
        int jj = tid;
        int j = ((jj>>6)<<8) + (q<<6) + (jj&63);
        zc_l[jj] = zc[b*N4D + j];
        wy_l[jj] = wy[j];
        v_l[tid] = v[tid];
    }
    if (tid < CELLS){
        c0_l[tid]  = dec_c0[b*ND + q*CELLS + tid];
        wlh_l[tid] = W_lin[q*CELLS + tid];
    }
    if (tid < SLICE) wlc_l[tid] = W_lin[ND + q*SLICE + tid];
    float blin = b_lin[0];
    __syncthreads();

    for (int t=0; t<NS; ++t){
        // ---- A: fetch h(t-1), y(t-1); hproj = h @ WhT ----
        if (tid < ND) h_l[tid] = ld_agf(&hG[b*ND + tid]);
        if (tid == 0){
            float y = 0.f;
            if (t > 0){
                y = blin + ld_agf(&yG[b*G+0]) + ld_agf(&yG[b*G+1])
                         + ld_agf(&yG[b*G+2]) + ld_agf(&yG[b*G+3]);
                if (q == 0) out[(size_t)b*NS + (t-1)] = y;
            }
            yprev = y;
        }
        __syncthreads();
        {
            int d2 = tid & 127, kq = tid >> 7;
            float ax = 0.f, ay = 0.f;
            #pragma unroll 8
            for (int kk=0; kk<32; ++kk){
                int k = kq*32 + kk;
                unsigned w = WhTp[k*128 + d2];
                float hvv = h_l[k];
                ax = fmaf(hvv, blo(w), ax); ay = fmaf(hvv, bhi(w), ay);
            }
            ((float2*)part)[kq*128 + d2] = make_float2(ax, ay);
        }
        __syncthreads();
        if (tid < ND){
            float s = 0.f;
            #pragma unroll
            for (int r=0;r<8;++r) s += part[r*256 + tid];
            hv[tid] = make_float2(v_l[tid], s);
        }
        __syncthreads();
        // ---- B: scores from LDS ep ----
        {
            int sl = tid & 127, dg = tid >> 7;
            float sc = 0.f;
            const unsigned* epl = ep_lds + dg*16*128 + sl;
            #pragma unroll
            for (int k16=0; k16<16; ++k16){
                unsigned w = epl[k16*128];
                int d = dg*32 + 2*k16;
                float2 a0 = hv[d], a1 = hv[d+1];
                sc += a0.x*ftanh(blo(w) + a0.y) + a1.x*ftanh(bhi(w) + a1.y);
            }
            part[dg*128 + sl] = sc;
        }
        __syncthreads();
        if (tid < SLICE){
            float s = 0.f;
            #pragma unroll
            for (int r=0;r<8;++r) s += part[r*128 + tid];
            part[1024 + tid] = s;
            float wm = wave_max(s);
            if ((tid&63)==0) wred[tid>>6] = wm;
        }
        __syncthreads();
        if (tid == 0) smax = fmaxf(wred[0], wred[1]);
        __syncthreads();
        if (tid < SLICE){
            float ev = __expf(part[1024 + tid] - smax);
            scores_l[tid] = ev;
            float s = wave_sum(ev);
            if ((tid&63)==0) wred[2+(tid>>6)] = s;
        }
        __syncthreads();
        if (tid == 0){
            st_agf(&msG[(b*G+q)*2+0], smax);
            st_agf(&msG[(b*G+q)*2+1], wred[2]+wred[3]);
        }
        // ---- C: context partial from registers ----
        {
            int ep2 = tid & 255, sq = tid >> 8;
            float ax = 0.f, ay = 0.f;
            #pragma unroll
            for (int ss=0; ss<32; ++ss){
                unsigned w = eo_reg[ss];
                float sc = scores_l[sq*32 + ss];
                ax = fmaf(sc, blo(w), ax); ay = fmaf(sc, bhi(w), ay);
            }
            ((float2*)part)[sq*256 + ep2] = make_float2(ax, ay);
        }
        __syncthreads();
        if (tid < NTE){
            float s = part[tid] + part[512+tid] + part[1024+tid] + part[1536+tid];
            st_agf(&ctxG[(size_t)(b*G+q)*NTE + tid], s);
        }
        groupbar(&ctr[b], (unsigned)(t*2*G + G), tid);
        // ---- D: merge softmax+context; z slice; gates; y partial ----
        if (tid < 2*G) msbuf[tid] = ld_agf(&msG[b*G*2 + tid]);
        __syncthreads();
        float mm = fmaxf(fmaxf(msbuf[0], msbuf[2]), fmaxf(msbuf[4], msbuf[6]));
        float w0 = __expf(msbuf[0]-mm), w1 = __expf(msbuf[2]-mm),
              w2 = __expf(msbuf[4]-mm), w3 = __expf(msbuf[6]-mm);
        float inv = __fdividef(1.f, msbuf[1]*w0 + msbuf[3]*w1 + msbuf[5]*w2 + msbuf[7]*w3);
        if (tid < NTE){
            const float* cg = ctxG + (size_t)b*G*NTE + tid;
            float cacc = ld_agf(cg)*w0 + ld_agf(cg+NTE)*w1
                       + ld_agf(cg+2*NTE)*w2 + ld_agf(cg+3*NTE)*w3;
            ctx_l[tid] = cacc * inv;
        }
        __syncthreads();
        {
            int jj2 = tid & 127, eq = tid >> 7;
            float ax = 0.f, ay = 0.f;
            #pragma unroll 8
            for (int ee=0; ee<64; ++ee){
                int e = eq*64 + ee;
                unsigned w = WdTp[e*128 + jj2];
                float cv = ctx_l[e];
                ax = fmaf(cv, blo(w), ax); ay = fmaf(cv, bhi(w), ay);
            }
            ((float2*)part)[eq*128 + jj2] = make_float2(ax, ay);
        }
        __syncthreads();
        if (tid < 256){
            float s = zc_l[tid] + yprev*wy_l[tid];
            #pragma unroll
            for (int r=0;r<8;++r) s += part[r*256 + tid];
            z_l[tid] = s;
        }
        __syncthreads();
        float yp = 0.f;
        if (tid < CELLS){
            float zi=z_l[tid], zf=z_l[64+tid], zg=z_l[128+tid], zo=z_l[192+tid];
            float cn = fsig(zf)*c0_l[tid] + fsig(zi)*ftanh(zg);
            float hn = fsig(zo)*ftanh(cn);
            st_agf(&hG[b*ND + q*CELLS + tid], hn);
            yp = hn * wlh_l[tid];
        } else if (tid < CELLS + SLICE){
            yp = ctx_l[q*SLICE + (tid - CELLS)] * wlc_l[tid - CELLS];
        }
        {
            float s = wave_sum(yp);
            if ((tid&63)==0 && tid < 192) wred[8+(tid>>6)] = s;
        }
        __syncthreads();
        if (tid == 0) st_agf(&yG[b*G + q], wred[8]+wred[9]+wred[10]);
        groupbar(&ctr[b], (unsigned)(t*2*G + 2*G), tid);
    }
    if (q == 0 && tid == 0){
        out[(size_t)b*NS + (NS-1)] = blin + ld_agf(&yG[b*G+0]) + ld_agf(&yG[b*G+1])
                                          + ld_agf(&yG[b*G+2]) + ld_agf(&yG[b*G+3]);
    }
}

extern "C" void kernel_launch(void* const* d_in, const int* in_sizes, int n_in,
                              void* d_out, int out_size, void* d_ws, size_t ws_size,
                              hipStream_t stream){
    const float* x      = (const float*)d_in[0];
    const float* enc_h0 = (const float*)d_in[1];
    const float* enc_c0 = (const float*)d_in[2];
    const float* dec_h0 = (const float*)d_in[3];
    const float* dec_c0 = (const float*)d_in[4];
    const float* Wih_f  = (const float*)d_in[5];
    const float* Whh_f  = (const float*)d_in[6];
    const float* b_f    = (const float*)d_in[7];
    const float* Wih_b  = (const float*)d_in[8];
    const float* Whh_b  = (const float*)d_in[9];
    const float* b_b    = (const float*)d_in[10];
    const float* W_attn = (const float*)d_in[11];
    const float* b_attn = (const float*)d_in[12];
    const float* v      = (const float*)d_in[13];
    const float* Wih_d  = (const float*)d_in[14];
    const float* Whh_d  = (const float*)d_in[15];
    const float* b_d    = (const float*)d_in[16];
    const float* W_lin  = (const float*)d_in[17];
    const float* b_lin  = (const float*)d_in[18];
    float* out = (float*)d_out;
    char* ws   = (char*)d_ws;

    size_t off = 0;
    auto alloc = [&](size_t bytes)->size_t{ size_t o = off; off += (bytes + 255) & ~(size_t)255; return o; };
    size_t o_eo16   = alloc((size_t)NB*NS*NTE*2);        // bf16 enc_out
    size_t o_eppk   = alloc((size_t)NB*G*128*128*4);     // packed bf16 ep
    size_t o_whhPKf = alloc((size_t)N4E*128*4);
    size_t o_whhPKb = alloc((size_t)N4E*128*4);
    size_t o_wihPKf = alloc((size_t)N4E*32*4);
    size_t o_wihPKb = alloc((size_t)N4E*32*4);
    size_t o_WhT16  = alloc((size_t)ND*ND*2);
    size_t o_WeT    = alloc((size_t)NTE*ND*4);
    size_t o_WdTg   = alloc((size_t)G*NTE*256*2);
    size_t o_WhhTd  = alloc((size_t)ND*N4D*4);
    size_t o_zc     = alloc((size_t)NB*N4D*4);
    size_t o_wy     = alloc((size_t)N4D*4);
    size_t o_hG     = alloc((size_t)NB*ND*4);
    size_t o_yG     = alloc((size_t)NB*G*4);
    size_t o_ctxG   = alloc((size_t)NB*G*NTE*4);
    size_t o_msG    = alloc((size_t)NB*G*2*4);
    size_t o_ctr    = alloc((size_t)NB*4);
    if (ws_size < off) return;

    auto F   = [&](size_t o)->float*{ return (float*)(ws + o); };
    auto U32 = [&](size_t o)->unsigned*{ return (unsigned*)(ws + o); };
    auto H16 = [&](size_t o)->__hip_bfloat16*{ return (__hip_bfloat16*)(ws + o); };

    auto T32 = [&](size_t dsto, const float* src, int R, int C, int ld, int offc){
        int n = R*C;
        k_transpose<<<dim3((n+255)/256), dim3(256), 0, stream>>>(F(dsto), src, R, C, ld, offc);
    };
    auto T16 = [&](size_t dsto, const float* src, int R, int C, int ld, int offc){
        int n = R*C;
        k_transpose16<<<dim3((n+255)/256), dim3(256), 0, stream>>>(H16(dsto), src, R, C, ld, offc);
    };
    auto PK = [&](size_t dsto, const float* src, int R, int Cp){
        int n = R*Cp;
        k_pack_pairs<<<dim3((n+255)/256), dim3(256), 0, stream>>>(U32(dsto), src, n, Cp);
    };
    PK(o_whhPKf, Whh_f, N4E, 128);
    PK(o_whhPKb, Whh_b, N4E, 128);
    PK(o_wihPKf, Wih_f, N4E, 32);
    PK(o_wihPKb, Wih_b, N4E, 32);
    T16(o_WhT16, W_attn, ND, ND, ND+NTE, 0);
    T32(o_WeT,   W_attn, ND, NTE, ND+NTE, ND);
    T32(o_WhhTd, Whh_d, N4D, ND, ND, 0);
    k_pack_wdtg<<<dim3((G*NTE*256)/256), dim3(256), 0, stream>>>(H16(o_WdTg), Wih_d);
    k_pack_wy<<<dim3(4), dim3(256), 0, stream>>>(F(o_wy), Wih_d);
    k_zc<<<dim3(NB), dim3(256), 0, stream>>>(F(o_zc), F(o_WhhTd), dec_h0, b_d);
    k_dec_init<<<dim3(NB), dim3(256), 0, stream>>>(F(o_hG), F(o_yG), (unsigned*)(ws+o_ctr), dec_h0);

    k_enc<<<dim3(2*NB), dim3(1024), 0, stream>>>(x, enc_h0, enc_c0,
        U32(o_whhPKf), U32(o_wihPKf), b_f, U32(o_whhPKb), U32(o_wihPKb), b_b, U32(o_eo16));

    k_encproj<<<dim3(NS/16, NB), dim3(256), 0, stream>>>(U32(o_eo16), F(o_WeT), b_attn,
        (unsigned short*)(ws+o_eppk));

    k_dec<<<dim3(NB*G), dim3(1024), 0, stream>>>(U32(o_eo16), U32(o_eppk),
        U32(o_WhT16), v, F(o_zc), F(o_wy), U32(o_WdTg), dec_c0, W_lin, b_lin,
        F(o_hG), F(o_yG), F(o_ctxG), F(o_msG), (unsigned*)(ws+o_ctr), out);
}

// Round 5
// 18346.683 us; speedup vs baseline: 2.2446x; 2.2446x over previous
//
#include <hip/hip_runtime.h>
#include <hip/hip_bf16.h>

#define NB 64
#define NS 512
#define NI 64
#define NE 256
#define ND 256
#define N4E 1024
#define N4D 1024
#define NTE 512   // 2*E
#define G 4
#define SLICE 128 // NS/G
#define CELLS 64  // ND/G

__device__ __forceinline__ float fsig(float x){
    return __fdividef(1.f, 1.f + __expf(-x));
}
__device__ __forceinline__ float ftanh(float x){
    x = fminf(10.f, fmaxf(-10.f, x));
    float e = __expf(2.f*x);
    return 1.f - __fdividef(2.f, e + 1.f);
}
__device__ __forceinline__ float wave_sum(float v){
    #pragma unroll
    for (int o=32;o>0;o>>=1) v += __shfl_xor(v, o, 64);
    return v;
}
__device__ __forceinline__ float wave_max(float v){
    #pragma unroll
    for (int o=32;o>0;o>>=1) v = fmaxf(v, __shfl_xor(v, o, 64));
    return v;
}
__device__ __forceinline__ float blo(unsigned u){ return __uint_as_float(u<<16); }
__device__ __forceinline__ float bhi(unsigned u){ return __uint_as_float(u & 0xffff0000u); }
__device__ __forceinline__ unsigned short bfbits(float f){
    __hip_bfloat16 h = __float2bfloat16(f);
    return *(unsigned short*)&h;
}
// relaxed agent-scope accessors: single instructions, no cache-wide ops
__device__ __forceinline__ float ld_agf(const float* p){
    return __hip_atomic_load(p, __ATOMIC_RELAXED, __HIP_MEMORY_SCOPE_AGENT);
}
__device__ __forceinline__ void st_agf(float* p, float v){
    __hip_atomic_store(p, v, __ATOMIC_RELAXED, __HIP_MEMORY_SCOPE_AGENT);
}

// flag barrier: __syncthreads drains each wave's stores (compiler emits
// vmcnt(0) before s_barrier) -> data visible before the flag store.
// Per-q flag words: no atomic RMW contention; 4 lanes poll in parallel.
__device__ __forceinline__ void groupbar(unsigned* flags, int b, int q,
                                         unsigned tgt, int tid){
    __syncthreads();
    if (tid == 0)
        __hip_atomic_store(&flags[b*4+q], tgt, __ATOMIC_RELAXED, __HIP_MEMORY_SCOPE_AGENT);
    if (tid < 4){
        while (__hip_atomic_load(&flags[b*4+tid], __ATOMIC_RELAXED,
                                 __HIP_MEMORY_SCOPE_AGENT) < tgt)
            __builtin_amdgcn_s_sleep(1);
    }
    __syncthreads();
}

// fp32 transpose: dst[c*R + r] = src[r*ld + off + c]
__global__ void k_transpose(float* __restrict__ dst, const float* __restrict__ src,
                            int R, int C, int ld, int off){
    int idx = blockIdx.x*256 + threadIdx.x;
    if (idx >= R*C) return;
    int r = idx / C, c = idx - r*C;
    dst[(size_t)c*R + r] = src[(size_t)r*ld + off + c];
}
// bf16 transpose
__global__ void k_transpose16(__hip_bfloat16* __restrict__ dst, const float* __restrict__ src,
                              int R, int C, int ld, int off){
    int idx = blockIdx.x*256 + threadIdx.x;
    if (idx >= R*C) return;
    int r = idx / C, c = idx - r*C;
    dst[(size_t)c*R + r] = __float2bfloat16(src[(size_t)r*ld + off + c]);
}

__global__ void k_pack_wy(float* __restrict__ wy, const float* __restrict__ Wih_d){
    int j = blockIdx.x*256 + threadIdx.x;
    if (j < N4D) wy[j] = Wih_d[(size_t)j*(NTE+1)];
}

// WdTg16[q][e][jj] = bf16(Wih_d[ (jj>>6)*256 + q*64 + (jj&63) ][ 1 + e ])
__global__ void k_pack_wdtg(__hip_bfloat16* __restrict__ dst, const float* __restrict__ Wih_d){
    int idx = blockIdx.x*256 + threadIdx.x;   // total 4*512*256 = 524288
    int q = idx >> 17, rem = idx & 131071;
    int e = rem >> 8, jj = rem & 255;
    int j = ((jj>>6)<<8) + (q<<6) + (jj&63);
    dst[idx] = __float2bfloat16(Wih_d[(size_t)j*(NTE+1) + 1 + e]);
}

// zc[b][j] = b_d[j] + sum_d h0d[b][d] * Whh_d[j][d]   (WhhTd is [d][j] fp32)
__global__ void k_zc(float* __restrict__ zc, const float* __restrict__ WhhTd,
                     const float* __restrict__ h0d, const float* __restrict__ b_d){
    int b = blockIdx.x, tid = threadIdx.x;
    __shared__ float h0[ND];
    if (tid < ND) h0[tid] = h0d[b*ND + tid];
    __syncthreads();
    for (int j = tid; j < N4D; j += 256){
        float acc = b_d[j];
        #pragma unroll 8
        for (int d=0; d<ND; ++d) acc = fmaf(h0[d], WhhTd[d*N4D + j], acc);
        zc[b*N4D + j] = acc;
    }
}

__global__ void k_dec_init(float* __restrict__ hG, float* __restrict__ yG,
                           unsigned* __restrict__ flags, const float* __restrict__ dec_h0){
    int b = blockIdx.x, tid = threadIdx.x;
    hG[b*ND + tid] = dec_h0[b*ND + tid];
    if (tid < G) yG[b*G + tid] = 0.f;
    if (tid < G) flags[b*G + tid] = 0u;
}

// Encoder v3: 128 blocks = (dir,b), 1024 threads = (j2 in [0,512), kh in {0,1}).
// r3's coalesced [d][j-pair] u32 layout; 2-way k-split halves per-thread loads;
// LDS combine; 4 accumulators for ILP; double-buffered x.
__global__ __launch_bounds__(1024) void k_enc(
    const float* __restrict__ x, const float* __restrict__ eh0, const float* __restrict__ ec0,
    const unsigned* __restrict__ whhTf, const unsigned* __restrict__ wihTf, const float* __restrict__ bf,
    const unsigned* __restrict__ whhTb, const unsigned* __restrict__ wihTb, const float* __restrict__ bb,
    unsigned* __restrict__ eo32)
{
    int bid = blockIdx.x;
    int b = bid & 63, dir = bid >> 6;
    int tid = threadIdx.x;
    int j2 = tid & 511, kh = tid >> 9;
    const unsigned* whh = dir ? whhTb : whhTf;   // [d][512 u32]
    const unsigned* wih = dir ? wihTb : wihTf;   // [i][512 u32]
    const float* bias = dir ? bb : bf;

    __shared__ __align__(16) float h_l[NE];
    __shared__ __align__(16) float xt[2][NI];
    __shared__ float zp0[N4E], zp1[N4E];

    float2 bias2 = make_float2(0.f, 0.f);
    if (kh == 0) bias2 = ((const float2*)bias)[j2];

    float cst = 0.f;
    if (tid < NE){
        h_l[tid] = eh0[(dir*NB+b)*NE + tid];
        cst      = ec0[(dir*NB+b)*NE + tid];
    }
    {
        int st0 = dir ? (NS-1) : 0;
        if (tid < 16) ((float4*)xt[0])[tid] = ((const float4*)(x + ((size_t)b*NS+st0)*NI))[tid];
    }
    __syncthreads();

    const unsigned* wihK = wih + (size_t)(kh*32)*512 + j2;
    const unsigned* whhK = whh + (size_t)(kh*128)*512 + j2;
    float* zpme = kh ? zp1 : zp0;

    for (int t=0;t<NS;++t){
        int st = dir ? (NS-1-t) : t;
        float4 xpre = make_float4(0.f,0.f,0.f,0.f);
        if (t+1 < NS && tid < 16){
            int stn = dir ? (NS-2-t) : (t+1);
            xpre = ((const float4*)(x + ((size_t)b*NS+stn)*NI))[tid];
        }
        const float* xc = xt[t&1];
        float x0=bias2.x, y0=bias2.y, x1=0.f, y1=0.f;
        #pragma unroll 8
        for (int ii=0; ii<32; ii+=2){
            int i = kh*32 + ii;
            unsigned wa = wihK[(size_t)ii*512];
            unsigned wb = wihK[(size_t)(ii+1)*512];
            float xa = xc[i], xb = xc[i+1];
            x0 = fmaf(xa, blo(wa), x0); y0 = fmaf(xa, bhi(wa), y0);
            x1 = fmaf(xb, blo(wb), x1); y1 = fmaf(xb, bhi(wb), y1);
        }
        #pragma unroll 8
        for (int dd=0; dd<128; dd+=2){
            int d = kh*128 + dd;
            unsigned wa = whhK[(size_t)dd*512];
            unsigned wb = whhK[(size_t)(dd+1)*512];
            float ha = h_l[d], hb = h_l[d+1];
            x0 = fmaf(ha, blo(wa), x0); y0 = fmaf(ha, bhi(wa), y0);
            x1 = fmaf(hb, blo(wb), x1); y1 = fmaf(hb, bhi(wb), y1);
        }
        ((float2*)zpme)[j2] = make_float2(x0+x1, y0+y1);
        if (t+1 < NS && tid < 16) ((float4*)xt[(t+1)&1])[tid] = xpre;
        __syncthreads();
        if (tid < NE){
            int c = tid;
            float zi = zp0[c]        + zp1[c];
            float zf = zp0[NE+c]     + zp1[NE+c];
            float zg = zp0[2*NE+c]   + zp1[2*NE+c];
            float zo = zp0[3*NE+c]   + zp1[3*NE+c];
            cst = fsig(zf)*cst + fsig(zi)*ftanh(zg);
            float hn = fsig(zo)*ftanh(cst);
            h_l[c] = hn;
            ((unsigned short*)eo32)[((size_t)b*NS+st)*NTE + dir*NE + c] = bfbits(hn);
        }
        __syncthreads();
    }
}

// ep_pk[b][q][dp][s] (u32 = bf16 pair d=2dp,2dp+1) from bf16 enc_out.
__global__ __launch_bounds__(256) void k_encproj(const unsigned* __restrict__ eo32,
        const float* __restrict__ WeT, const float* __restrict__ b_attn,
        unsigned short* __restrict__ ep_pk16){
    int b = blockIdx.y, s0 = blockIdx.x*16, tid = threadIdx.x;
    __shared__ float tile[16*NTE];
    {
        const unsigned* eop = eo32 + (size_t)(b*NS + s0)*256;
        for (int k=0;k<32;++k){
            int wi = k*256 + tid;
            unsigned w = eop[wi];
            int sl = wi>>8, ew = wi&255;
            tile[sl*NTE + 2*ew]   = blo(w);
            tile[sl*NTE + 2*ew+1] = bhi(w);
        }
    }
    __syncthreads();
    float acc[16];
    float ba = b_attn[tid];
    #pragma unroll
    for (int sl=0;sl<16;++sl) acc[sl]=ba;
    #pragma unroll 4
    for (int e4=0;e4<128;++e4){
        float w0 = WeT[(4*e4+0)*ND+tid];
        float w1 = WeT[(4*e4+1)*ND+tid];
        float w2 = WeT[(4*e4+2)*ND+tid];
        float w3 = WeT[(4*e4+3)*ND+tid];
        #pragma unroll
        for (int sl=0;sl<16;++sl){
            const float4 tv = *(const float4*)&tile[sl*NTE + 4*e4];
            acc[sl] = fmaf(tv.x,w0,fmaf(tv.y,w1,fmaf(tv.z,w2,fmaf(tv.w,w3,acc[sl]))));
        }
    }
    #pragma unroll
    for (int sl=0;sl<16;++sl){
        int s = s0+sl;
        size_t wdi = ((size_t)(b*4 + (s>>7))*128 + (tid>>1))*128 + (s&127);
        ep_pk16[wdi*2 + (tid&1)] = bfbits(acc[sl]);
    }
}

// Cooperative decoder: 256 blocks = 64 batches x 4 slices, 1024 threads.
__global__ __launch_bounds__(1024, 4) void k_dec(
    const unsigned* __restrict__ eo32,     // [b*s][256] bf16 e-pairs
    const unsigned* __restrict__ ep_pk,    // [b][q][128 dp][128 s] u32
    const unsigned* __restrict__ WhTp,     // [k 256][128] bf16 d-pairs
    const float* __restrict__ v,
    const float* __restrict__ zc, const float* __restrict__ wy,
    const unsigned* __restrict__ WdTp_all, // [q][512 e][128] bf16 jj-pairs
    const float* __restrict__ dec_c0,
    const float* __restrict__ W_lin, const float* __restrict__ b_lin,
    float* __restrict__ hG, float* __restrict__ yG,
    float* __restrict__ ctxG, float* __restrict__ msG,
    unsigned* __restrict__ flags,
    float* __restrict__ out)
{
    int bid = blockIdx.x;
    int b = bid & 63, q = bid >> 6;
    int tid = threadIdx.x;

    __shared__ unsigned ep_lds[16384];   // 64 KB: [128 dp][128 s]
    __shared__ float part[2048];
    __shared__ float h_l[ND];
    __shared__ float2 hv[ND];            // (v[d], hproj[d])
    __shared__ float v_l[ND];
    __shared__ float scores_l[SLICE];
    __shared__ float ctx_l[NTE];
    __shared__ float z_l[256], zc_l[256], wy_l[256];
    __shared__ float c0_l[CELLS], wlh_l[CELLS], wlc_l[SLICE];
    __shared__ float msbuf[8];
    __shared__ float wred[16];
    __shared__ float smax, yprev;

    const unsigned* WdTp = WdTp_all + (size_t)q*NTE*128;

    for (int i=tid; i<16384; i+=1024)
        ep_lds[i] = ep_pk[(size_t)(b*4+q)*16384 + i];
    unsigned eo_reg[32];
    {
        int ep2 = tid & 255, sq = tid >> 8;
        const unsigned* eop = eo32 + (size_t)(b*NS + q*SLICE + sq*32)*256 + ep2;
        #pragma unroll
        for (int ss=0; ss<32; ++ss) eo_reg[ss] = eop[(size_t)ss*256];
    }
    if (tid < 256){
        int jj = tid;
        int j = ((jj>>6)<<8) + (q<<6) + (jj&63);
        zc_l[jj] = zc[b*N4D + j];
        wy_l[jj] = wy[j];
        v_l[tid] = v[tid];
    }
    if (tid < CELLS){
        c0_l[tid]  = dec_c0[b*ND + q*CELLS + tid];
        wlh_l[tid] = W_lin[q*CELLS + tid];
    }
    if (tid < SLICE) wlc_l[tid] = W_lin[ND + q*SLICE + tid];
    float blin = b_lin[0];
    __syncthreads();

    for (int t=0; t<NS; ++t){
        // ---- A: fetch h(t-1), y(t-1); hproj = h @ WhT ----
        if (tid < ND) h_l[tid] = ld_agf(&hG[b*ND + tid]);
        if (tid == 0){
            float y = 0.f;
            if (t > 0){
                y = blin + ld_agf(&yG[b*G+0]) + ld_agf(&yG[b*G+1])
                         + ld_agf(&yG[b*G+2]) + ld_agf(&yG[b*G+3]);
                if (q == 0) out[(size_t)b*NS + (t-1)] = y;
            }
            yprev = y;
        }
        __syncthreads();
        {
            int d2 = tid & 127, kq = tid >> 7;
            float ax = 0.f, ay = 0.f;
            #pragma unroll 8
            for (int kk=0; kk<32; ++kk){
                int k = kq*32 + kk;
                unsigned w = WhTp[k*128 + d2];
                float hvv = h_l[k];
                ax = fmaf(hvv, blo(w), ax); ay = fmaf(hvv, bhi(w), ay);
            }
            ((float2*)part)[kq*128 + d2] = make_float2(ax, ay);
        }
        __syncthreads();
        if (tid < ND){
            float s = 0.f;
            #pragma unroll
            for (int r=0;r<8;++r) s += part[r*256 + tid];
            hv[tid] = make_float2(v_l[tid], s);
        }
        __syncthreads();
        // ---- B: scores from LDS ep ----
        {
            int sl = tid & 127, dg = tid >> 7;
            float sc = 0.f;
            const unsigned* epl = ep_lds + dg*16*128 + sl;
            #pragma unroll
            for (int k16=0; k16<16; ++k16){
                unsigned w = epl[k16*128];
                int d = dg*32 + 2*k16;
                float2 a0 = hv[d], a1 = hv[d+1];
                sc += a0.x*ftanh(blo(w) + a0.y) + a1.x*ftanh(bhi(w) + a1.y);
            }
            part[dg*128 + sl] = sc;
        }
        __syncthreads();
        if (tid < SLICE){
            float s = 0.f;
            #pragma unroll
            for (int r=0;r<8;++r) s += part[r*128 + tid];
            part[1024 + tid] = s;
            float wm = wave_max(s);
            if ((tid&63)==0) wred[tid>>6] = wm;
        }
        __syncthreads();
        if (tid == 0) smax = fmaxf(wred[0], wred[1]);
        __syncthreads();
        if (tid < SLICE){
            float ev = __expf(part[1024 + tid] - smax);
            scores_l[tid] = ev;
            float s = wave_sum(ev);
            if ((tid&63)==0) wred[2+(tid>>6)] = s;
        }
        __syncthreads();
        if (tid == 0){
            st_agf(&msG[(b*G+q)*2+0], smax);
            st_agf(&msG[(b*G+q)*2+1], wred[2]+wred[3]);
        }
        // ---- C: context partial from registers ----
        {
            int ep2 = tid & 255, sq = tid >> 8;
            float ax = 0.f, ay = 0.f;
            #pragma unroll
            for (int ss=0; ss<32; ++ss){
                unsigned w = eo_reg[ss];
                float sc = scores_l[sq*32 + ss];
                ax = fmaf(sc, blo(w), ax); ay = fmaf(sc, bhi(w), ay);
            }
            ((float2*)part)[sq*256 + ep2] = make_float2(ax, ay);
        }
        __syncthreads();
        if (tid < NTE){
            float s = part[tid] + part[512+tid] + part[1024+tid] + part[1536+tid];
            st_agf(&ctxG[(size_t)(b*G+q)*NTE + tid], s);
        }
        groupbar(flags, b, q, (unsigned)(2*t+1), tid);
        // ---- D: merge softmax+context (ms + ctx loads issued together) ----
        float cg0=0.f, cg1=0.f, cg2=0.f, cg3=0.f;
        if (tid < 2*G) msbuf[tid] = ld_agf(&msG[b*G*2 + tid]);
        if (tid < NTE){
            const float* cg = ctxG + (size_t)b*G*NTE + tid;
            cg0 = ld_agf(cg);        cg1 = ld_agf(cg+NTE);
            cg2 = ld_agf(cg+2*NTE);  cg3 = ld_agf(cg+3*NTE);
        }
        __syncthreads();
        float mm = fmaxf(fmaxf(msbuf[0], msbuf[2]), fmaxf(msbuf[4], msbuf[6]));
        float w0 = __expf(msbuf[0]-mm), w1 = __expf(msbuf[2]-mm),
              w2 = __expf(msbuf[4]-mm), w3 = __expf(msbuf[6]-mm);
        float inv = __fdividef(1.f, msbuf[1]*w0 + msbuf[3]*w1 + msbuf[5]*w2 + msbuf[7]*w3);
        if (tid < NTE)
            ctx_l[tid] = (cg0*w0 + cg1*w1 + cg2*w2 + cg3*w3) * inv;
        __syncthreads();
        {
            int jj2 = tid & 127, eq = tid >> 7;
            float ax = 0.f, ay = 0.f;
            #pragma unroll 8
            for (int ee=0; ee<64; ++ee){
                int e = eq*64 + ee;
                unsigned w = WdTp[e*128 + jj2];
                float cv = ctx_l[e];
                ax = fmaf(cv, blo(w), ax); ay = fmaf(cv, bhi(w), ay);
            }
            ((float2*)part)[eq*128 + jj2] = make_float2(ax, ay);
        }
        __syncthreads();
        if (tid < 256){
            float s = zc_l[tid] + yprev*wy_l[tid];
            #pragma unroll
            for (int r=0;r<8;++r) s += part[r*256 + tid];
            z_l[tid] = s;
        }
        __syncthreads();
        float yp = 0.f;
        if (tid < CELLS){
            float zi=z_l[tid], zf=z_l[64+tid], zg=z_l[128+tid], zo=z_l[192+tid];
            float cn = fsig(zf)*c0_l[tid] + fsig(zi)*ftanh(zg);
            float hn = fsig(zo)*ftanh(cn);
            st_agf(&hG[b*ND + q*CELLS + tid], hn);
            yp = hn * wlh_l[tid];
        } else if (tid < CELLS + SLICE){
            yp = ctx_l[q*SLICE + (tid - CELLS)] * wlc_l[tid - CELLS];
        }
        {
            float s = wave_sum(yp);
            if ((tid&63)==0 && tid < 192) wred[8+(tid>>6)] = s;
        }
        __syncthreads();
        if (tid == 0) st_agf(&yG[b*G + q], wred[8]+wred[9]+wred[10]);
        groupbar(flags, b, q, (unsigned)(2*t+2), tid);
    }
    if (q == 0 && tid == 0){
        out[(size_t)b*NS + (NS-1)] = blin + ld_agf(&yG[b*G+0]) + ld_agf(&yG[b*G+1])
                                          + ld_agf(&yG[b*G+2]) + ld_agf(&yG[b*G+3]);
    }
}

extern "C" void kernel_launch(void* const* d_in, const int* in_sizes, int n_in,
                              void* d_out, int out_size, void* d_ws, size_t ws_size,
                              hipStream_t stream){
    const float* x      = (const float*)d_in[0];
    const float* enc_h0 = (const float*)d_in[1];
    const float* enc_c0 = (const float*)d_in[2];
    const float* dec_h0 = (const float*)d_in[3];
    const float* dec_c0 = (const float*)d_in[4];
    const float* Wih_f  = (const float*)d_in[5];
    const float* Whh_f  = (const float*)d_in[6];
    const float* b_f    = (const float*)d_in[7];
    const float* Wih_b  = (const float*)d_in[8];
    const float* Whh_b  = (const float*)d_in[9];
    const float* b_b    = (const float*)d_in[10];
    const float* W_attn = (const float*)d_in[11];
    const float* b_attn = (const float*)d_in[12];
    const float* v      = (const float*)d_in[13];
    const float* Wih_d  = (const float*)d_in[14];
    const float* Whh_d  = (const float*)d_in[15];
    const float* b_d    = (const float*)d_in[16];
    const float* W_lin  = (const float*)d_in[17];
    const float* b_lin  = (const float*)d_in[18];
    float* out = (float*)d_out;
    char* ws   = (char*)d_ws;

    size_t off = 0;
    auto alloc = [&](size_t bytes)->size_t{ size_t o = off; off += (bytes + 255) & ~(size_t)255; return o; };
    size_t o_eo16   = alloc((size_t)NB*NS*NTE*2);        // bf16 enc_out
    size_t o_eppk   = alloc((size_t)NB*G*128*128*4);     // packed bf16 ep
    size_t o_WihTf  = alloc((size_t)NI*N4E*2);           // [i][1024 j] bf16
    size_t o_WhhTf  = alloc((size_t)NE*N4E*2);           // [d][1024 j] bf16
    size_t o_WihTb  = alloc((size_t)NI*N4E*2);
    size_t o_WhhTb  = alloc((size_t)NE*N4E*2);
    size_t o_WhT16  = alloc((size_t)ND*ND*2);
    size_t o_WeT    = alloc((size_t)NTE*ND*4);
    size_t o_WdTg   = alloc((size_t)G*NTE*256*2);
    size_t o_WhhTd  = alloc((size_t)ND*N4D*4);
    size_t o_zc     = alloc((size_t)NB*N4D*4);
    size_t o_wy     = alloc((size_t)N4D*4);
    size_t o_hG     = alloc((size_t)NB*ND*4);
    size_t o_yG     = alloc((size_t)NB*G*4);
    size_t o_ctxG   = alloc((size_t)NB*G*NTE*4);
    size_t o_msG    = alloc((size_t)NB*G*2*4);
    size_t o_flags  = alloc((size_t)NB*G*4);
    if (ws_size < off) return;

    auto F   = [&](size_t o)->float*{ return (float*)(ws + o); };
    auto U32 = [&](size_t o)->unsigned*{ return (unsigned*)(ws + o); };
    auto H16 = [&](size_t o)->__hip_bfloat16*{ return (__hip_bfloat16*)(ws + o); };

    auto T32 = [&](size_t dsto, const float* src, int R, int C, int ld, int offc){
        int n = R*C;
        k_transpose<<<dim3((n+255)/256), dim3(256), 0, stream>>>(F(dsto), src, R, C, ld, offc);
    };
    auto T16 = [&](size_t dsto, const float* src, int R, int C, int ld, int offc){
        int n = R*C;
        k_transpose16<<<dim3((n+255)/256), dim3(256), 0, stream>>>(H16(dsto), src, R, C, ld, offc);
    };
    T16(o_WihTf, Wih_f, N4E, NI, NI, 0);
    T16(o_WhhTf, Whh_f, N4E, NE, NE, 0);
    T16(o_WihTb, Wih_b, N4E, NI, NI, 0);
    T16(o_WhhTb, Whh_b, N4E, NE, NE, 0);
    T16(o_WhT16, W_attn, ND, ND, ND+NTE, 0);
    T32(o_WeT,   W_attn, ND, NTE, ND+NTE, ND);
    T32(o_WhhTd, Whh_d, N4D, ND, ND, 0);
    k_pack_wdtg<<<dim3((G*NTE*256)/256), dim3(256), 0, stream>>>(H16(o_WdTg), Wih_d);
    k_pack_wy<<<dim3(4), dim3(256), 0, stream>>>(F(o_wy), Wih_d);
    k_zc<<<dim3(NB), dim3(256), 0, stream>>>(F(o_zc), F(o_WhhTd), dec_h0, b_d);
    k_dec_init<<<dim3(NB), dim3(256), 0, stream>>>(F(o_hG), F(o_yG), (unsigned*)(ws+o_flags), dec_h0);

    k_enc<<<dim3(2*NB), dim3(1024), 0, stream>>>(x, enc_h0, enc_c0,
        U32(o_WhhTf), U32(o_WihTf), b_f, U32(o_WhhTb), U32(o_WihTb), b_b, U32(o_eo16));

    k_encproj<<<dim3(NS/16, NB), dim3(256), 0, stream>>>(U32(o_eo16), F(o_WeT), b_attn,
        (unsigned short*)(ws+o_eppk));

    k_dec<<<dim3(NB*G), dim3(1024), 0, stream>>>(U32(o_eo16), U32(o_eppk),
        U32(o_WhT16), v, F(o_zc), F(o_wy), U32(o_WdTg), dec_c0, W_lin, b_lin,
        F(o_hG), F(o_yG), F(o_ctxG), F(o_msG), (unsigned*)(ws+o_flags), out);
}